// Round 3
// baseline (399.071 us; speedup 1.0000x reference)
//
#include <hip/hip_runtime.h>
#include <cstdint>
#include <cstddef>

// SelfAttention: B=8, S=2048, D=512, fp32 in/out.
// R7b: R7 with cvt_pkrtz return-type fix (__fp16x2, bit-cast to u32).
//  - Phase A: 32x32x16 MFMA, swapped operands (S^T = K·Q^T). K A-frags from
//    LDS (reads halved vs 16x16), Q B-frags in regs. Softmax key-axis is
//    lane-local: in-lane max tree + shfl_xor(32) + kh-pair LDS combine.
//  - V never touches LDS: 16 global_load_dwordx4 per wave per kt, prefetched
//    at top of kt, consumed as phase-C B-frags from registers (V^T L2-resident).
//  - K double-buffered (2x64KB LDS): K(kt+1) issued at top of kt, waited one
//    full iteration later. 3 barriers/kt.
//  - l (softmax denom) kept in LDS (lrun[64]), updated by kh==0 waves.
// ws: [qh 16M][kh 16M][vh 16M][vt 16M (xh aliases)][Wt 1.5M] = 65.5 MiB.

#define SEQ 2048
#define DIM 512
#define NB 8
#define BSZ (NB * SEQ)
#define KT 64
#define NT (SEQ / KT)

typedef __attribute__((ext_vector_type(8))) _Float16 half8;
typedef __attribute__((ext_vector_type(2))) __fp16 fp16x2;
typedef __attribute__((ext_vector_type(4))) float f32x4;
typedef __attribute__((ext_vector_type(16))) float f32x16;

__device__ __forceinline__ unsigned short f2h(float f) {
  _Float16 h = (_Float16)f;
  return __builtin_bit_cast(unsigned short, h);
}
__device__ __forceinline__ half8 ld_frag(const unsigned short* p) {
  return *(const half8*)(const void*)p;
}
__device__ __forceinline__ void gl_lds16(const unsigned short* g, unsigned short* l) {
  __builtin_amdgcn_global_load_lds(
      (__attribute__((address_space(1))) void*)g,
      (__attribute__((address_space(3))) void*)l, 16, 0, 0);
}
// Fused waitcnt+barrier (single asm block: nothing schedules between them).
__device__ __forceinline__ void bar_vm0() {
  asm volatile("s_waitcnt vmcnt(0)\ns_barrier" ::: "memory");
}
__device__ __forceinline__ void bar_lgkm() {
  asm volatile("s_waitcnt lgkmcnt(0)\ns_barrier" ::: "memory");
}
__device__ __forceinline__ void bar_lgkm_vm0() {
  asm volatile("s_waitcnt lgkmcnt(0) vmcnt(0)\ns_barrier" ::: "memory");
}

// ---------------------------------------------------------------------------
__global__ __launch_bounds__(256) void cvt_x_kernel(
    const float* __restrict__ X, unsigned short* __restrict__ xh)
{
  size_t i0 = ((size_t)blockIdx.x * 256 + threadIdx.x) * 8;
  float4 a = *(const float4*)&X[i0];
  float4 b = *(const float4*)&X[i0 + 4];
  ushort4 o0; o0.x = f2h(a.x); o0.y = f2h(a.y); o0.z = f2h(a.z); o0.w = f2h(a.w);
  ushort4 o1; o1.x = f2h(b.x); o1.y = f2h(b.y); o1.z = f2h(b.z); o1.w = f2h(b.w);
  *(ushort4*)&xh[i0] = o0;
  *(ushort4*)&xh[i0 + 4] = o1;
}

// ---------------------------------------------------------------------------
__global__ __launch_bounds__(256) void cvt_w_kernel(
    const float* __restrict__ Wq, const float* __restrict__ Wk,
    const float* __restrict__ Wv, unsigned short* __restrict__ Wt)
{
  const int z = blockIdx.z;
  const float* W = (z == 0) ? Wq : (z == 1) ? Wk : Wv;
  unsigned short* out = Wt + (size_t)z * DIM * DIM;
  const int k0 = blockIdx.x * 64, n0 = blockIdx.y * 64;
  const int t = threadIdx.x;
  __shared__ unsigned short tl[64 * 72];
#pragma unroll
  for (int i = 0; i < 4; i++) {
    int f = t + 256 * i;
    int kr = f >> 4, c4 = (f & 15) * 4;
    float4 v = *(const float4*)&W[(size_t)(k0 + kr) * DIM + n0 + c4];
    tl[(c4 + 0) * 72 + kr] = f2h(v.x);
    tl[(c4 + 1) * 72 + kr] = f2h(v.y);
    tl[(c4 + 2) * 72 + kr] = f2h(v.z);
    tl[(c4 + 3) * 72 + kr] = f2h(v.w);
  }
  __syncthreads();
#pragma unroll
  for (int i = 0; i < 2; i++) {
    int f = t + 256 * i;
    int nr = f >> 3, k8 = (f & 7) * 8;
    *(uint4*)&out[(size_t)(n0 + nr) * DIM + k0 + k8] = *(const uint4*)&tl[nr * 72 + k8];
  }
}

// ---------------------------------------------------------------------------
// proj (unchanged): qkv[z] = fp16(xh @ Wt[z]^T + b[z]).
// ---------------------------------------------------------------------------
__global__ __launch_bounds__(256) void proj_kernel(
    const unsigned short* __restrict__ xh, const unsigned short* __restrict__ Wt,
    const float* __restrict__ bq, const float* __restrict__ bk,
    const float* __restrict__ bv, unsigned short* __restrict__ outbase)
{
  const int z = blockIdx.z;
  const unsigned short* Wz = Wt + (size_t)z * DIM * DIM;
  const float* bias = (z == 0) ? bq : (z == 1) ? bk : bv;
  unsigned short* out = outbase + (size_t)z * BSZ * DIM;
  const int m0 = blockIdx.x * 128, n0 = blockIdx.y * 128;
  const int t = threadIdx.x, lane = t & 63, wave = t >> 6;
  const int wrow = (wave >> 1) * 64, wcol = (wave & 1) * 64;
  const int lr = lane & 15, lq = (lane >> 4) * 8;

  __shared__ unsigned short sm[128 * 132];
  unsigned short* As = sm;
  unsigned short* Bs = sm + 128 * 64;

  f32x4 acc[4][4];
  const f32x4 zero = {0.f, 0.f, 0.f, 0.f};
#pragma unroll
  for (int r = 0; r < 4; r++)
#pragma unroll
    for (int c = 0; c < 4; c++) acc[r][c] = zero;

  for (int k0 = 0; k0 < DIM; k0 += 64) {
    __syncthreads();
#pragma unroll
    for (int i = 0; i < 4; i++) {
      int f = t + 256 * i;
      int row = f >> 3, c8 = (f & 7) * 8;
      gl_lds16(&xh[(size_t)(m0 + row) * DIM + k0 + c8], &As[i * 2048 + wave * 512]);
      gl_lds16(&Wz[(size_t)(n0 + row) * DIM + k0 + c8], &Bs[i * 2048 + wave * 512]);
    }
    __syncthreads();
#pragma unroll
    for (int kk = 0; kk < 64; kk += 32) {
      half8 a[4], b[4];
#pragma unroll
      for (int r = 0; r < 4; r++) a[r] = ld_frag(&As[(wrow + 16 * r + lr) * 64 + kk + lq]);
#pragma unroll
      for (int c = 0; c < 4; c++) b[c] = ld_frag(&Bs[(wcol + 16 * c + lr) * 64 + kk + lq]);
#pragma unroll
      for (int r = 0; r < 4; r++)
#pragma unroll
        for (int c = 0; c < 4; c++)
          acc[r][c] = __builtin_amdgcn_mfma_f32_16x16x32_f16(a[r], b[c], acc[r][c], 0, 0, 0);
    }
  }
  __syncthreads();
#pragma unroll
  for (int c = 0; c < 4; c++) {
    float bb = bias[n0 + wcol + 16 * c + lr];
#pragma unroll
    for (int r = 0; r < 4; r++)
#pragma unroll
      for (int e = 0; e < 4; e++)
        sm[(wrow + 16 * r + (lane >> 4) * 4 + e) * 132 + wcol + 16 * c + lr] =
            f2h(acc[r][c][e] + bb);
  }
  __syncthreads();
#pragma unroll
  for (int i = 0; i < 8; i++) {
    int f = t + 256 * i;
    int row = f >> 4, c8 = (f & 15) * 8;
    *(uint4*)&out[(size_t)(m0 + row) * DIM + n0 + c8] = *(const uint4*)&sm[row * 132 + c8];
  }
}

// ---------------------------------------------------------------------------
__global__ __launch_bounds__(256) void vtrans_kernel(
    const unsigned short* __restrict__ vh, unsigned short* __restrict__ vt)
{
  const int b = blockIdx.z;
  const int s0 = blockIdx.x * 64, n0 = blockIdx.y * 64;
  const int t = threadIdx.x;
  __shared__ unsigned short tl[64 * 72];
#pragma unroll
  for (int i = 0; i < 2; i++) {
    int f = t + 256 * i;
    int sr = f >> 3, c8 = (f & 7) * 8;
    uint4 raw = *(const uint4*)&vh[((size_t)b * SEQ + s0 + sr) * DIM + n0 + c8];
    unsigned short u[8];
    *(uint4*)u = raw;
#pragma unroll
    for (int j = 0; j < 8; j++) tl[(c8 + j) * 72 + sr] = u[j];
  }
  __syncthreads();
#pragma unroll
  for (int i = 0; i < 2; i++) {
    int f = t + 256 * i;
    int nr = f >> 3, s8 = (f & 7) * 8;
    *(uint4*)&vt[((size_t)b * DIM + n0 + nr) * SEQ + s0 + s8] = *(const uint4*)&tl[nr * 72 + s8];
  }
}

// ---------------------------------------------------------------------------
// flash R7. Block = 64 Q rows, 4 waves: wave = (kh = wave&1, rh = wave>>1),
// owns the 32x32 S^T tile [keys kh*32..+32][qrows rh*32..+32] in phase A and
// d-slice [wave*128..+128] x all 64 rows in phase C.
// Per kt: top bar (K(kt) landed) -> issue V(kt)->regs, K(kt+1)->other buffer
//   -> A: 32x ds_read_b128 + 32x mfma_32x32x16 (S^T = K·Q^T)
//   -> B: in-lane max tree + shfl32 + mpart exchange (bar#1); exp, pack f16,
//        P->Pbuf, in-lane sum + shfl32 + lpart (bar#2); lrun update (kh0)
//   -> rescale acc (abuf), pf from Pbuf, C: 64x mfma_16x16x32 (V from regs).
// ---------------------------------------------------------------------------
#define PSTR 72   // Pbuf row stride (halves); 144B = 16B-aligned b128 rows
#define OSTR 516  // Obuf row stride (floats)

__global__ __launch_bounds__(256, 1) void flash_kernel(
    const unsigned short* __restrict__ Qb, const unsigned short* __restrict__ Kb,
    const unsigned short* __restrict__ Vtb, float* __restrict__ Ob)
{
  const int zb = blockIdx.x & 7;          // batch -> XCD affinity
  const int q0 = (blockIdx.x >> 3) * 64;  // q-tile base row
  const unsigned short* Q = Qb + (size_t)zb * SEQ * DIM;
  const unsigned short* K = Kb + (size_t)zb * SEQ * DIM;
  const unsigned short* V = Vtb + (size_t)zb * DIM * SEQ;  // [d][s]
  float* Out = Ob + (size_t)zb * SEQ * DIM;

  const int t = threadIdx.x, lane = t & 63, wave = t >> 6;
  const int l31 = lane & 31, hi = lane >> 5;
  const int kh = wave & 1, rh = wave >> 1;
  const int lr = lane & 15, lq4 = lane >> 4;
  const float L2E = 1.4426950408889634f;

  // LDS carve (halves): KA 32768 | KB 32768 | Pbuf 64*72 | mpart[2][64] |
  // lpart[2][64] | abuf[64] | lrun[64]  = 141824 B total.
  __shared__ unsigned short lds[70912];
  unsigned short* KA = lds;
  unsigned short* KB = lds + 32768;
  unsigned short* Pbuf = lds + 65536;
  float* mpart = (float*)(lds + 65536 + 64 * PSTR);
  float* lpart = mpart + 128;
  float* abuf = lpart + 128;
  float* lrun = abuf + 64;

  if (t < 64) lrun[t] = 0.f;

  // staging offsets: tile [64 rows][512 halves], 64 chunks of 8h per row,
  // source chunk = lds chunk ^ (row&7). Per instr i: row = 4i+wave, lane = chunk.
  int koff[16];
#pragma unroll
  for (int i = 0; i < 16; i++) {
    int f = t + 256 * i;
    int row = f >> 6, c = f & 63;
    koff[i] = row * DIM + (c ^ (row & 7)) * 8;
  }

  // ---- stage Q -> KA, read Q B-frags (qrow = rh*32 + l31, k = hi*8) ----
#pragma unroll
  for (int i = 0; i < 16; i++)
    gl_lds16(&Q[(size_t)q0 * DIM + koff[i]], &KA[i * 2048 + wave * 512]);
  bar_lgkm_vm0();
  half8 qf[32];
  {
    const int qrow = rh * 32 + l31;
    const int qsw = qrow & 7;
#pragma unroll
    for (int j = 0; j < 32; j++)
      qf[j] = ld_frag(&KA[qrow * 512 + (((2 * j + hi) ^ qsw) << 3)]);
  }
  __syncthreads();  // all qf reads done before K(0) overwrites KA

  // issue K(0) -> KA
#pragma unroll
  for (int i = 0; i < 16; i++)
    gl_lds16(&K[koff[i]], &KA[i * 2048 + wave * 512]);

  // ---- running state ----
  f32x4 acc[32];  // [rg 0..3][dc 0..7]: row rg*16+lq4*4+e, d wave*128+dc*16+lr
  const f32x4 zero = {0.f, 0.f, 0.f, 0.f};
#pragma unroll
  for (int ob = 0; ob < 32; ob++) acc[ob] = zero;
  float m_run = -__builtin_inff();  // per lane: row rh*32 + l31

  const unsigned short* cur = KA;
  unsigned short* nxt = KB;

  for (int kt = 0; kt < NT; kt++) {
    bar_vm0();  // K(kt) landed (each wave's own gl_lds + collective barrier)

    // ---- prefetch V(kt) -> regs (B-frags: d-col = lr, keys at lq4*8) ----
    half8 vf[16];
    {
      const unsigned short* Vb = V + (size_t)(wave * 128 + lr) * SEQ + kt * KT + lq4 * 8;
#pragma unroll
      for (int dc = 0; dc < 8; dc++)
#pragma unroll
        for (int ks = 0; ks < 2; ks++)
          vf[dc * 2 + ks] = ld_frag(Vb + (size_t)dc * 16 * SEQ + ks * 32);
    }
    // ---- issue K(kt+1) -> nxt (flies a full iteration) ----
    if (kt + 1 < NT) {
      const unsigned short* Kt = K + (size_t)(kt + 1) * KT * DIM;
#pragma unroll
      for (int i = 0; i < 16; i++)
        gl_lds16(&Kt[koff[i]], &nxt[i * 2048 + wave * 512]);
    }

    // ===== phase A: S^T = K·Q^T (32x32 tile; A=K from LDS, B=Q regs) =====
    f32x16 sacc = {0.f, 0.f, 0.f, 0.f, 0.f, 0.f, 0.f, 0.f,
                   0.f, 0.f, 0.f, 0.f, 0.f, 0.f, 0.f, 0.f};
    {
      const int keyrow = kh * 32 + l31;
      const int ksw = keyrow & 7;
      const unsigned short* Kc = cur + keyrow * 512;
#pragma unroll
      for (int j = 0; j < 32; j++) {
        half8 kf = ld_frag(&Kc[(((2 * j + hi) ^ ksw) << 3)]);
        sacc = __builtin_amdgcn_mfma_f32_32x32x16_f16(kf, qf[j], sacc, 0, 0, 0);
      }
    }

    // ===== phase B: online softmax; lane owns row rh*32+l31, 16 keys in regs =====
    float mx = sacc[0];
#pragma unroll
    for (int i2 = 1; i2 < 16; i2++) mx = fmaxf(mx, sacc[i2]);
    mx = fmaxf(mx, __shfl_xor(mx, 32, 64));
    if (lane < 32) mpart[kh * 64 + rh * 32 + lane] = mx;
    bar_lgkm();  // #1
    float mo = mpart[(kh ^ 1) * 64 + rh * 32 + l31];
    float mnew = fmaxf(m_run, fmaxf(mx, mo));
    float alpha = exp2f((m_run - mnew) * L2E);
    m_run = mnew;
    if (kh == 0 && lane < 32) abuf[rh * 32 + lane] = alpha;
    // p = exp(S - m), pack to f16 pairs, write P[row][key] (key = C-layout row)
    float psum = 0.f;
    {
      const int prow = rh * 32 + l31;
#pragma unroll
      for (int w = 0; w < 8; w++) {
        float p0 = exp2f((sacc[2 * w] - mnew) * L2E);
        float p1 = exp2f((sacc[2 * w + 1] - mnew) * L2E);
        psum += p0 + p1;
        fp16x2 pk = __builtin_amdgcn_cvt_pkrtz(p0, p1);
        int keyoff = (w >> 1) * 8 + (w & 1) * 2 + 4 * hi;
        *(unsigned int*)&Pbuf[prow * PSTR + kh * 32 + keyoff] =
            __builtin_bit_cast(unsigned int, pk);
      }
    }
    psum += __shfl_xor(psum, 32, 64);
    if (lane < 32) lpart[kh * 64 + rh * 32 + lane] = psum;
    bar_lgkm();  // #2: P, abuf, lpart visible
    if (kh == 0 && lane < 32) {
      int r = rh * 32 + lane;
      lrun[r] = alpha * lrun[r] + lpart[r] + lpart[64 + r];
    }

    // ---- rescale acc by alpha (broadcast reads from abuf) ----
#pragma unroll
    for (int rg = 0; rg < 4; rg++)
#pragma unroll
      for (int e = 0; e < 4; e++) {
        float a = abuf[rg * 16 + lq4 * 4 + e];
#pragma unroll
        for (int dc = 0; dc < 8; dc++) acc[rg * 8 + dc][e] *= a;
      }

    // ===== phase C: O += P V (wave: all 64 rows x its 128-d slice) =====
    half8 pf[4][2];
#pragma unroll
    for (int rg = 0; rg < 4; rg++)
#pragma unroll
      for (int ks = 0; ks < 2; ks++)
        pf[rg][ks] = ld_frag(&Pbuf[(rg * 16 + lr) * PSTR + ks * 32 + lq4 * 8]);
#pragma unroll
    for (int dc = 0; dc < 8; dc++)
#pragma unroll
      for (int rg = 0; rg < 4; rg++) {
        acc[rg * 8 + dc] =
            __builtin_amdgcn_mfma_f32_16x16x32_f16(pf[rg][0], vf[dc * 2 + 0],
                                                   acc[rg * 8 + dc], 0, 0, 0);
        acc[rg * 8 + dc] =
            __builtin_amdgcn_mfma_f32_16x16x32_f16(pf[rg][1], vf[dc * 2 + 1],
                                                   acc[rg * 8 + dc], 0, 0, 0);
      }

    { const unsigned short* tmp = cur; cur = nxt; nxt = (unsigned short*)tmp; }
  }

  bar_lgkm_vm0();  // lrun final, all LDS quiesced before Obuf reuse

  // ---- finalize: O /= l, repack via LDS in 32-row halves, coalesced stores ----
  float linv[4][4];
#pragma unroll
  for (int rg = 0; rg < 4; rg++)
#pragma unroll
    for (int e = 0; e < 4; e++) linv[rg][e] = 1.0f / lrun[rg * 16 + lq4 * 4 + e];

  float* Obuf = (float*)lds;  // 32 x OSTR floats = 66 KB (over KA/KB)
#pragma unroll
  for (int h = 0; h < 2; h++) {
    __syncthreads();
#pragma unroll
    for (int r2 = 0; r2 < 2; r2++) {
      int rg = h * 2 + r2;
#pragma unroll
      for (int e = 0; e < 4; e++) {
        int rowh = r2 * 16 + lq4 * 4 + e;
#pragma unroll
        for (int dc = 0; dc < 8; dc++)
          Obuf[rowh * OSTR + wave * 128 + dc * 16 + lr] = acc[rg * 8 + dc][e] * linv[rg][e];
      }
    }
    __syncthreads();
#pragma unroll
    for (int i = 0; i < 16; i++) {
      int f = t + 256 * i;
      int rowh = f >> 7, c4 = (f & 127) * 4;
      *(float4*)&Out[(size_t)(q0 + h * 32 + rowh) * DIM + c4] =
          *(const float4*)&Obuf[rowh * OSTR + c4];
    }
  }
}

// ---------------------------------------------------------------------------
extern "C" void kernel_launch(void* const* d_in, const int* in_sizes, int n_in,
                              void* d_out, int out_size, void* d_ws, size_t ws_size,
                              hipStream_t stream)
{
  const float* X  = (const float*)d_in[0];
  const float* Wq = (const float*)d_in[1];
  const float* bq = (const float*)d_in[2];
  const float* Wk = (const float*)d_in[3];
  const float* bk = (const float*)d_in[4];
  const float* Wv = (const float*)d_in[5];
  const float* bv = (const float*)d_in[6];
  float* Out = (float*)d_out;

  char* ws = (char*)d_ws;
  const size_t MB = 1u << 20;
  unsigned short* qh = (unsigned short*)(ws);            // 16 MiB
  unsigned short* kh = (unsigned short*)(ws + 16 * MB);  // 16 MiB (proj z=1)
  unsigned short* vh = (unsigned short*)(ws + 32 * MB);  // 16 MiB (proj z=2)
  unsigned short* vt = (unsigned short*)(ws + 48 * MB);  // 16 MiB
  unsigned short* xh = (unsigned short*)(ws + 48 * MB);  // alias vt: dead pre-vtrans
  unsigned short* Wt = (unsigned short*)(ws + 64 * MB);  // 1.5 MiB

  cvt_x_kernel<<<dim3(BSZ * DIM / 2048), 256, 0, stream>>>(X, xh);
  cvt_w_kernel<<<dim3(8, 8, 3), 256, 0, stream>>>(Wq, Wk, Wv, Wt);
  proj_kernel<<<dim3(BSZ / 128, DIM / 128, 3), 256, 0, stream>>>(
      xh, Wt, bq, bk, bv, qh);
  vtrans_kernel<<<dim3(SEQ / 64, DIM / 64, NB), 256, 0, stream>>>(vh, vt);
  flash_kernel<<<dim3(NB * SEQ / 64), 256, 0, stream>>>(qh, kh, vt, Out);
}

// Round 7
// 306.542 us; speedup vs baseline: 1.3018x; 1.3018x over previous
//
#include <hip/hip_runtime.h>
#include <cstdint>
#include <cstddef>

// SelfAttention: B=8, S=2048, D=512, fp32 in/out.
// R8 (third resubmit; three broker timeouts in a row, kernel has never run).
//  - Q LDS-resident (64KB, staged once); phase A reads K AND Q frags from LDS
//    (frees the 128-VGPR qf array that caused R7b's spill).
//  - Phase A: 32x32x16 swapped (S^T = K·Q^T), TWO independent MFMA chains.
//  - K single-buffered: K(kt+1) issued after bar#1 (A-reads drained) into the
//    same Kbuf, waited at next loop-top vmcnt(0) barrier (full B+C cover).
//  - V from global into regs in two 32-reg halves (vfA top, vfB after bar#1).
//  - Lane-local softmax (in-lane max over 16 regs + shfl32 + kh-pair via LDS).
// Peak VGPR ~245 (acc 128 + pf/vfA/vfB 96 + temps) -> no spill.
// ws: [qh 16M][kh 16M][vh 16M][vt 16M (xh aliases)][Wt 1.5M] = 65.5 MiB.

#define SEQ 2048
#define DIM 512
#define NB 8
#define BSZ (NB * SEQ)
#define KT 64
#define NT (SEQ / KT)

typedef __attribute__((ext_vector_type(8))) _Float16 half8;
typedef __attribute__((ext_vector_type(2))) __fp16 fp16x2;
typedef __attribute__((ext_vector_type(4))) float f32x4;
typedef __attribute__((ext_vector_type(16))) float f32x16;

__device__ __forceinline__ unsigned short f2h(float f) {
  _Float16 h = (_Float16)f;
  return __builtin_bit_cast(unsigned short, h);
}
__device__ __forceinline__ half8 ld_frag(const unsigned short* p) {
  return *(const half8*)(const void*)p;
}
__device__ __forceinline__ void gl_lds16(const unsigned short* g, unsigned short* l) {
  __builtin_amdgcn_global_load_lds(
      (__attribute__((address_space(1))) void*)g,
      (__attribute__((address_space(3))) void*)l, 16, 0, 0);
}
// Fused waitcnt+barrier (single asm block: nothing schedules between them).
__device__ __forceinline__ void bar_vm0() {
  asm volatile("s_waitcnt vmcnt(0)\ns_barrier" ::: "memory");
}
__device__ __forceinline__ void bar_lgkm() {
  asm volatile("s_waitcnt lgkmcnt(0)\ns_barrier" ::: "memory");
}
__device__ __forceinline__ void bar_lgkm_vm0() {
  asm volatile("s_waitcnt lgkmcnt(0) vmcnt(0)\ns_barrier" ::: "memory");
}

// ---------------------------------------------------------------------------
__global__ __launch_bounds__(256) void cvt_x_kernel(
    const float* __restrict__ X, unsigned short* __restrict__ xh)
{
  size_t i0 = ((size_t)blockIdx.x * 256 + threadIdx.x) * 8;
  float4 a = *(const float4*)&X[i0];
  float4 b = *(const float4*)&X[i0 + 4];
  ushort4 o0; o0.x = f2h(a.x); o0.y = f2h(a.y); o0.z = f2h(a.z); o0.w = f2h(a.w);
  ushort4 o1; o1.x = f2h(b.x); o1.y = f2h(b.y); o1.z = f2h(b.z); o1.w = f2h(b.w);
  *(ushort4*)&xh[i0] = o0;
  *(ushort4*)&xh[i0 + 4] = o1;
}

// ---------------------------------------------------------------------------
__global__ __launch_bounds__(256) void cvt_w_kernel(
    const float* __restrict__ Wq, const float* __restrict__ Wk,
    const float* __restrict__ Wv, unsigned short* __restrict__ Wt)
{
  const int z = blockIdx.z;
  const float* W = (z == 0) ? Wq : (z == 1) ? Wk : Wv;
  unsigned short* out = Wt + (size_t)z * DIM * DIM;
  const int k0 = blockIdx.x * 64, n0 = blockIdx.y * 64;
  const int t = threadIdx.x;
  __shared__ unsigned short tl[64 * 72];
#pragma unroll
  for (int i = 0; i < 4; i++) {
    int f = t + 256 * i;
    int kr = f >> 4, c4 = (f & 15) * 4;
    float4 v = *(const float4*)&W[(size_t)(k0 + kr) * DIM + n0 + c4];
    tl[(c4 + 0) * 72 + kr] = f2h(v.x);
    tl[(c4 + 1) * 72 + kr] = f2h(v.y);
    tl[(c4 + 2) * 72 + kr] = f2h(v.z);
    tl[(c4 + 3) * 72 + kr] = f2h(v.w);
  }
  __syncthreads();
#pragma unroll
  for (int i = 0; i < 2; i++) {
    int f = t + 256 * i;
    int nr = f >> 3, k8 = (f & 7) * 8;
    *(uint4*)&out[(size_t)(n0 + nr) * DIM + k0 + k8] = *(const uint4*)&tl[nr * 72 + k8];
  }
}

// ---------------------------------------------------------------------------
// proj (unchanged): qkv[z] = fp16(xh @ Wt[z]^T + b[z]).
// ---------------------------------------------------------------------------
__global__ __launch_bounds__(256) void proj_kernel(
    const unsigned short* __restrict__ xh, const unsigned short* __restrict__ Wt,
    const float* __restrict__ bq, const float* __restrict__ bk,
    const float* __restrict__ bv, unsigned short* __restrict__ outbase)
{
  const int z = blockIdx.z;
  const unsigned short* Wz = Wt + (size_t)z * DIM * DIM;
  const float* bias = (z == 0) ? bq : (z == 1) ? bk : bv;
  unsigned short* out = outbase + (size_t)z * BSZ * DIM;
  const int m0 = blockIdx.x * 128, n0 = blockIdx.y * 128;
  const int t = threadIdx.x, lane = t & 63, wave = t >> 6;
  const int wrow = (wave >> 1) * 64, wcol = (wave & 1) * 64;
  const int lr = lane & 15, lq = (lane >> 4) * 8;

  __shared__ unsigned short sm[128 * 132];
  unsigned short* As = sm;
  unsigned short* Bs = sm + 128 * 64;

  f32x4 acc[4][4];
  const f32x4 zero = {0.f, 0.f, 0.f, 0.f};
#pragma unroll
  for (int r = 0; r < 4; r++)
#pragma unroll
    for (int c = 0; c < 4; c++) acc[r][c] = zero;

  for (int k0 = 0; k0 < DIM; k0 += 64) {
    __syncthreads();
#pragma unroll
    for (int i = 0; i < 4; i++) {
      int f = t + 256 * i;
      int row = f >> 3, c8 = (f & 7) * 8;
      gl_lds16(&xh[(size_t)(m0 + row) * DIM + k0 + c8], &As[i * 2048 + wave * 512]);
      gl_lds16(&Wz[(size_t)(n0 + row) * DIM + k0 + c8], &Bs[i * 2048 + wave * 512]);
    }
    __syncthreads();
#pragma unroll
    for (int kk = 0; kk < 64; kk += 32) {
      half8 a[4], b[4];
#pragma unroll
      for (int r = 0; r < 4; r++) a[r] = ld_frag(&As[(wrow + 16 * r + lr) * 64 + kk + lq]);
#pragma unroll
      for (int c = 0; c < 4; c++) b[c] = ld_frag(&Bs[(wcol + 16 * c + lr) * 64 + kk + lq]);
#pragma unroll
      for (int r = 0; r < 4; r++)
#pragma unroll
        for (int c = 0; c < 4; c++)
          acc[r][c] = __builtin_amdgcn_mfma_f32_16x16x32_f16(a[r], b[c], acc[r][c], 0, 0, 0);
    }
  }
  __syncthreads();
#pragma unroll
  for (int c = 0; c < 4; c++) {
    float bb = bias[n0 + wcol + 16 * c + lr];
#pragma unroll
    for (int r = 0; r < 4; r++)
#pragma unroll
      for (int e = 0; e < 4; e++)
        sm[(wrow + 16 * r + (lane >> 4) * 4 + e) * 132 + wcol + 16 * c + lr] =
            f2h(acc[r][c][e] + bb);
  }
  __syncthreads();
#pragma unroll
  for (int i = 0; i < 8; i++) {
    int f = t + 256 * i;
    int row = f >> 4, c8 = (f & 15) * 8;
    *(uint4*)&out[(size_t)(m0 + row) * DIM + n0 + c8] = *(const uint4*)&sm[row * 132 + c8];
  }
}

// ---------------------------------------------------------------------------
__global__ __launch_bounds__(256) void vtrans_kernel(
    const unsigned short* __restrict__ vh, unsigned short* __restrict__ vt)
{
  const int b = blockIdx.z;
  const int s0 = blockIdx.x * 64, n0 = blockIdx.y * 64;
  const int t = threadIdx.x;
  __shared__ unsigned short tl[64 * 72];
#pragma unroll
  for (int i = 0; i < 2; i++) {
    int f = t + 256 * i;
    int sr = f >> 3, c8 = (f & 7) * 8;
    uint4 raw = *(const uint4*)&vh[((size_t)b * SEQ + s0 + sr) * DIM + n0 + c8];
    unsigned short u[8];
    *(uint4*)u = raw;
#pragma unroll
    for (int j = 0; j < 8; j++) tl[(c8 + j) * 72 + sr] = u[j];
  }
  __syncthreads();
#pragma unroll
  for (int i = 0; i < 2; i++) {
    int f = t + 256 * i;
    int nr = f >> 3, s8 = (f & 7) * 8;
    *(uint4*)&vt[((size_t)b * DIM + n0 + nr) * SEQ + s0 + s8] = *(const uint4*)&tl[nr * 72 + s8];
  }
}

// ---------------------------------------------------------------------------
// flash R8. Block = 64 Q rows, 4 waves: (kh = wave&1, rh = wave>>1).
// Per kt:
//   top bar_vm0 (K(kt) landed) -> issue vfA (V d 0..63 of wave slice)
//   -> A: 2x16 chained mfma_32x32x16, K+Q frags from LDS (S^T = K·Q^T)
//   -> max tree + shfl32 + mpart; bar#1 (lgkm: A-reads drained)
//   -> issue vfB + K(kt+1) into same Kbuf (cover = B+C+next-top)
//   -> exp/pack/Pbuf/lpart; bar#2 -> lrun, rescale acc, pf
//   -> C: 64x mfma_16x16x32, dc0-3 vfA / dc4-7 vfB (all 64 rows x 128-d slice)
// ---------------------------------------------------------------------------
#define PSTR 72   // Pbuf row stride (halves); 144B = 16B-aligned b128 rows
#define OSTR 516  // Obuf row stride (floats)

__global__ __launch_bounds__(256, 1) void flash_kernel(
    const unsigned short* __restrict__ Qb, const unsigned short* __restrict__ Kb,
    const unsigned short* __restrict__ Vtb, float* __restrict__ Ob)
{
  const int zb = blockIdx.x & 7;          // batch -> XCD affinity
  const int q0 = (blockIdx.x >> 3) * 64;  // q-tile base row
  const unsigned short* Q = Qb + (size_t)zb * SEQ * DIM;
  const unsigned short* K = Kb + (size_t)zb * SEQ * DIM;
  const unsigned short* V = Vtb + (size_t)zb * DIM * SEQ;  // [d][s]
  float* Out = Ob + (size_t)zb * SEQ * DIM;

  const int t = threadIdx.x, lane = t & 63, wave = t >> 6;
  const int l31 = lane & 31, hi = lane >> 5;
  const int kh = wave & 1, rh = wave >> 1;
  const int lr = lane & 15, lq4 = lane >> 4;
  const float L2E = 1.4426950408889634f;

  // LDS carve (halves): Qbuf 32768 | Kbuf 32768 | Pbuf 64*72 | mpart[2][64] |
  // lpart[2][64] | abuf[64] | lrun[64] = 141824 B total.
  __shared__ unsigned short lds[70912];
  unsigned short* Qbuf = lds;            // [64 rows][512], swizzled
  unsigned short* Kbuf = lds + 32768;    // [64 keys][512], swizzled
  unsigned short* Pbuf = lds + 65536;
  float* mpart = (float*)(lds + 65536 + 64 * PSTR);
  float* lpart = mpart + 128;
  float* abuf = lpart + 128;
  float* lrun = abuf + 64;

  if (t < 64) lrun[t] = 0.f;

  // staging offsets: tile [64 rows][512 halves], 64 chunks of 8h per row,
  // source chunk = lds chunk ^ (row&7).
  int koff[16];
#pragma unroll
  for (int i = 0; i < 16; i++) {
    int f = t + 256 * i;
    int row = f >> 6, c = f & 63;
    koff[i] = row * DIM + (c ^ (row & 7)) * 8;
  }

  // ---- stage Q -> Qbuf (resident), K(0) -> Kbuf; drained at loop-top bar ----
#pragma unroll
  for (int i = 0; i < 16; i++)
    gl_lds16(&Q[(size_t)q0 * DIM + koff[i]], &Qbuf[i * 2048 + wave * 512]);
#pragma unroll
  for (int i = 0; i < 16; i++)
    gl_lds16(&K[koff[i]], &Kbuf[i * 2048 + wave * 512]);

  // ---- running state ----
  f32x4 acc[32];  // [rg 0..3][dc 0..7]: row rg*16+lq4*4+e, d wave*128+dc*16+lr
  const f32x4 zero = {0.f, 0.f, 0.f, 0.f};
#pragma unroll
  for (int ob = 0; ob < 32; ob++) acc[ob] = zero;
  float m_run = -__builtin_inff();  // per lane: row rh*32 + l31

  const int keyrow = kh * 32 + l31, ksw = keyrow & 7;
  const int qrow = rh * 32 + l31, qsw = qrow & 7;
  const unsigned short* Kc = Kbuf + keyrow * 512;
  const unsigned short* Qc = Qbuf + qrow * 512;

  for (int kt = 0; kt < NT; kt++) {
    bar_vm0();  // K(kt) (and Q at kt=0) landed for all waves

    // ---- prefetch vfA: wave's d 0..63 slice (covered by phase A+B) ----
    const unsigned short* Vb = V + (size_t)(wave * 128 + lr) * SEQ + kt * KT + lq4 * 8;
    half8 vfA[8];
#pragma unroll
    for (int dc = 0; dc < 4; dc++)
#pragma unroll
      for (int ks = 0; ks < 2; ks++)
        vfA[dc * 2 + ks] = ld_frag(Vb + (size_t)dc * 16 * SEQ + ks * 32);

    // ===== phase A: S^T = K·Q^T, 2 independent chains (k 0..255 / 256..511) =====
    f32x16 s0 = {0.f, 0.f, 0.f, 0.f, 0.f, 0.f, 0.f, 0.f,
                 0.f, 0.f, 0.f, 0.f, 0.f, 0.f, 0.f, 0.f};
    f32x16 s1 = s0;
    __builtin_amdgcn_s_setprio(1);
#pragma unroll
    for (int j = 0; j < 16; j++) {
      half8 kf0 = ld_frag(&Kc[((2 * j + hi) ^ ksw) << 3]);
      half8 qv0 = ld_frag(&Qc[((2 * j + hi) ^ qsw) << 3]);
      half8 kf1 = ld_frag(&Kc[((2 * (j + 16) + hi) ^ ksw) << 3]);
      half8 qv1 = ld_frag(&Qc[((2 * (j + 16) + hi) ^ qsw) << 3]);
      s0 = __builtin_amdgcn_mfma_f32_32x32x16_f16(kf0, qv0, s0, 0, 0, 0);
      s1 = __builtin_amdgcn_mfma_f32_32x32x16_f16(kf1, qv1, s1, 0, 0, 0);
    }
    __builtin_amdgcn_s_setprio(0);
    f32x16 sacc = s0 + s1;

    // ===== phase B: online softmax; lane owns row rh*32+l31, 16 keys in regs =====
    float mx = sacc[0];
#pragma unroll
    for (int i2 = 1; i2 < 16; i2++) mx = fmaxf(mx, sacc[i2]);
    mx = fmaxf(mx, __shfl_xor(mx, 32, 64));
    if (lane < 32) mpart[kh * 64 + rh * 32 + lane] = mx;
    bar_lgkm();  // #1: mpart visible; ALL phase-A ds_reads drained block-wide

    // issue vfB (d 64..127 of slice) then K(kt+1) into same Kbuf (reads done)
    half8 vfB[8];
#pragma unroll
    for (int dc = 0; dc < 4; dc++)
#pragma unroll
      for (int ks = 0; ks < 2; ks++)
        vfB[dc * 2 + ks] = ld_frag(Vb + (size_t)(dc + 4) * 16 * SEQ + ks * 32);
    if (kt + 1 < NT) {
      const unsigned short* Kt = K + (size_t)(kt + 1) * KT * DIM;
#pragma unroll
      for (int i = 0; i < 16; i++)
        gl_lds16(&Kt[koff[i]], &Kbuf[i * 2048 + wave * 512]);
    }

    float mo = mpart[(kh ^ 1) * 64 + rh * 32 + l31];
    float mnew = fmaxf(m_run, fmaxf(mx, mo));
    float alpha = exp2f((m_run - mnew) * L2E);
    m_run = mnew;
    if (kh == 0 && lane < 32) abuf[rh * 32 + lane] = alpha;
    // p = exp(S - m), pack f16 pairs, write P[row][key] (key = C-layout row)
    float psum = 0.f;
#pragma unroll
    for (int w = 0; w < 8; w++) {
      float p0 = exp2f((sacc[2 * w] - mnew) * L2E);
      float p1 = exp2f((sacc[2 * w + 1] - mnew) * L2E);
      psum += p0 + p1;
      fp16x2 pk = __builtin_amdgcn_cvt_pkrtz(p0, p1);
      int keyoff = (w >> 1) * 8 + (w & 1) * 2 + 4 * hi;
      *(unsigned int*)&Pbuf[qrow * PSTR + kh * 32 + keyoff] =
          __builtin_bit_cast(unsigned int, pk);
    }
    psum += __shfl_xor(psum, 32, 64);
    if (lane < 32) lpart[kh * 64 + rh * 32 + lane] = psum;
    bar_lgkm();  // #2: Pbuf, abuf, lpart visible
    if (kh == 0 && lane < 32) {
      int r = rh * 32 + lane;
      lrun[r] = alpha * lrun[r] + lpart[r] + lpart[64 + r];
    }

    // ---- rescale acc by alpha (broadcast reads from abuf) ----
#pragma unroll
    for (int rg = 0; rg < 4; rg++)
#pragma unroll
      for (int e = 0; e < 4; e++) {
        float a = abuf[rg * 16 + lq4 * 4 + e];
#pragma unroll
        for (int dc = 0; dc < 8; dc++) acc[rg * 8 + dc][e] *= a;
      }

    // ===== phase C: O += P V (wave: all 64 rows x its 128-d slice) =====
    half8 pf[4][2];
#pragma unroll
    for (int rg = 0; rg < 4; rg++)
#pragma unroll
      for (int ks = 0; ks < 2; ks++)
        pf[rg][ks] = ld_frag(&Pbuf[(rg * 16 + lr) * PSTR + ks * 32 + lq4 * 8]);
    __builtin_amdgcn_s_setprio(1);
#pragma unroll
    for (int dc = 0; dc < 4; dc++)
#pragma unroll
      for (int rg = 0; rg < 4; rg++) {
        acc[rg * 8 + dc] =
            __builtin_amdgcn_mfma_f32_16x16x32_f16(pf[rg][0], vfA[dc * 2 + 0],
                                                   acc[rg * 8 + dc], 0, 0, 0);
        acc[rg * 8 + dc] =
            __builtin_amdgcn_mfma_f32_16x16x32_f16(pf[rg][1], vfA[dc * 2 + 1],
                                                   acc[rg * 8 + dc], 0, 0, 0);
      }
#pragma unroll
    for (int dc = 4; dc < 8; dc++)
#pragma unroll
      for (int rg = 0; rg < 4; rg++) {
        acc[rg * 8 + dc] =
            __builtin_amdgcn_mfma_f32_16x16x32_f16(pf[rg][0], vfB[(dc - 4) * 2 + 0],
                                                   acc[rg * 8 + dc], 0, 0, 0);
        acc[rg * 8 + dc] =
            __builtin_amdgcn_mfma_f32_16x16x32_f16(pf[rg][1], vfB[(dc - 4) * 2 + 1],
                                                   acc[rg * 8 + dc], 0, 0, 0);
      }
    __builtin_amdgcn_s_setprio(0);
  }

  bar_lgkm_vm0();  // lrun final, all LDS quiesced before Obuf reuse

  // ---- finalize: O /= l, repack via LDS in 32-row halves, coalesced stores ----
  float linv[4][4];
#pragma unroll
  for (int rg = 0; rg < 4; rg++)
#pragma unroll
    for (int e = 0; e < 4; e++) linv[rg][e] = 1.0f / lrun[rg * 16 + lq4 * 4 + e];

  float* Obuf = (float*)lds;  // 32 x OSTR floats = 66 KB (over Qbuf/Kbuf)
#pragma unroll
  for (int h = 0; h < 2; h++) {
    __syncthreads();
#pragma unroll
    for (int r2 = 0; r2 < 2; r2++) {
      int rg = h * 2 + r2;
#pragma unroll
      for (int e = 0; e < 4; e++) {
        int rowh = r2 * 16 + lq4 * 4 + e;
#pragma unroll
        for (int dc = 0; dc < 8; dc++)
          Obuf[rowh * OSTR + wave * 128 + dc * 16 + lr] = acc[rg * 8 + dc][e] * linv[rg][e];
      }
    }
    __syncthreads();
#pragma unroll
    for (int i = 0; i < 16; i++) {
      int f = t + 256 * i;
      int rowh = f >> 7, c4 = (f & 127) * 4;
      *(float4*)&Out[(size_t)(q0 + h * 32 + rowh) * DIM + c4] =
          *(const float4*)&Obuf[rowh * OSTR + c4];
    }
  }
}

// ---------------------------------------------------------------------------
extern "C" void kernel_launch(void* const* d_in, const int* in_sizes, int n_in,
                              void* d_out, int out_size, void* d_ws, size_t ws_size,
                              hipStream_t stream)
{
  const float* X  = (const float*)d_in[0];
  const float* Wq = (const float*)d_in[1];
  const float* bq = (const float*)d_in[2];
  const float* Wk = (const float*)d_in[3];
  const float* bk = (const float*)d_in[4];
  const float* Wv = (const float*)d_in[5];
  const float* bv = (const float*)d_in[6];
  float* Out = (float*)d_out;

  char* ws = (char*)d_ws;
  const size_t MB = 1u << 20;
  unsigned short* qh = (unsigned short*)(ws);            // 16 MiB
  unsigned short* kh = (unsigned short*)(ws + 16 * MB);  // 16 MiB (proj z=1)
  unsigned short* vh = (unsigned short*)(ws + 32 * MB);  // 16 MiB (proj z=2)
  unsigned short* vt = (unsigned short*)(ws + 48 * MB);  // 16 MiB
  unsigned short* xh = (unsigned short*)(ws + 48 * MB);  // alias vt: dead pre-vtrans
  unsigned short* Wt = (unsigned short*)(ws + 64 * MB);  // 1.5 MiB

  cvt_x_kernel<<<dim3(BSZ * DIM / 2048), 256, 0, stream>>>(X, xh);
  cvt_w_kernel<<<dim3(8, 8, 3), 256, 0, stream>>>(Wq, Wk, Wv, Wt);
  proj_kernel<<<dim3(BSZ / 128, DIM / 128, 3), 256, 0, stream>>>(
      xh, Wt, bq, bk, bv, qh);
  vtrans_kernel<<<dim3(SEQ / 64, DIM / 64, NB), 256, 0, stream>>>(vh, vt);
  flash_kernel<<<dim3(NB * SEQ / 64), 256, 0, stream>>>(qh, kh, vt, Out);
}

// Round 10
// 293.168 us; speedup vs baseline: 1.3612x; 1.0456x over previous
//
#include <hip/hip_runtime.h>
#include <cstdint>
#include <cstddef>

// SelfAttention: B=8, S=2048, D=512, fp32 in/out.
// R9 (third submit; two broker timeouts, never ran) = R8 + bank-conflict fixes:
//  1. Pbuf stride 72->68 halves (34 dwords/row, banks spread 2*row) + b64
//     granularity: P writes as 4x ds_write_b64 (w-pairs combined), pf reads as
//     2x ds_read_b64. Both verified 4-lanes/bank = conflict-free; PSTR=68
//     makes b128 fusion misaligned so the compiler cannot re-merge.
//  2. Defer-max (THR=8): per-row keep m_run when tile max grew <= 8 (P bounded
//     by e^8 < f16 max); block-uniform skip of the 128-mul acc rescale via
//     per-wave ballot flags in LDS, read after the existing bar#2.
//  3. K(kt+1) gl_lds issued immediately after bar#1 (before vfB loads).
// ws: [qh 16M][kh 16M][vh 16M][vt 16M (xh aliases)][Wt 1.5M] = 65.5 MiB.

#define SEQ 2048
#define DIM 512
#define NB 8
#define BSZ (NB * SEQ)
#define KT 64
#define NT (SEQ / KT)

typedef __attribute__((ext_vector_type(8))) _Float16 half8;
typedef __attribute__((ext_vector_type(4))) _Float16 half4;
typedef __attribute__((ext_vector_type(2))) __fp16 fp16x2;
typedef __attribute__((ext_vector_type(4))) float f32x4;
typedef __attribute__((ext_vector_type(16))) float f32x16;

__device__ __forceinline__ unsigned short f2h(float f) {
  _Float16 h = (_Float16)f;
  return __builtin_bit_cast(unsigned short, h);
}
__device__ __forceinline__ half8 ld_frag(const unsigned short* p) {
  return *(const half8*)(const void*)p;
}
__device__ __forceinline__ void gl_lds16(const unsigned short* g, unsigned short* l) {
  __builtin_amdgcn_global_load_lds(
      (__attribute__((address_space(1))) void*)g,
      (__attribute__((address_space(3))) void*)l, 16, 0, 0);
}
// Fused waitcnt+barrier (single asm block: nothing schedules between them).
__device__ __forceinline__ void bar_vm0() {
  asm volatile("s_waitcnt vmcnt(0)\ns_barrier" ::: "memory");
}
__device__ __forceinline__ void bar_lgkm() {
  asm volatile("s_waitcnt lgkmcnt(0)\ns_barrier" ::: "memory");
}
__device__ __forceinline__ void bar_lgkm_vm0() {
  asm volatile("s_waitcnt lgkmcnt(0) vmcnt(0)\ns_barrier" ::: "memory");
}

// ---------------------------------------------------------------------------
__global__ __launch_bounds__(256) void cvt_x_kernel(
    const float* __restrict__ X, unsigned short* __restrict__ xh)
{
  size_t i0 = ((size_t)blockIdx.x * 256 + threadIdx.x) * 8;
  float4 a = *(const float4*)&X[i0];
  float4 b = *(const float4*)&X[i0 + 4];
  ushort4 o0; o0.x = f2h(a.x); o0.y = f2h(a.y); o0.z = f2h(a.z); o0.w = f2h(a.w);
  ushort4 o1; o1.x = f2h(b.x); o1.y = f2h(b.y); o1.z = f2h(b.z); o1.w = f2h(b.w);
  *(ushort4*)&xh[i0] = o0;
  *(ushort4*)&xh[i0 + 4] = o1;
}

// ---------------------------------------------------------------------------
__global__ __launch_bounds__(256) void cvt_w_kernel(
    const float* __restrict__ Wq, const float* __restrict__ Wk,
    const float* __restrict__ Wv, unsigned short* __restrict__ Wt)
{
  const int z = blockIdx.z;
  const float* W = (z == 0) ? Wq : (z == 1) ? Wk : Wv;
  unsigned short* out = Wt + (size_t)z * DIM * DIM;
  const int k0 = blockIdx.x * 64, n0 = blockIdx.y * 64;
  const int t = threadIdx.x;
  __shared__ unsigned short tl[64 * 72];
#pragma unroll
  for (int i = 0; i < 4; i++) {
    int f = t + 256 * i;
    int kr = f >> 4, c4 = (f & 15) * 4;
    float4 v = *(const float4*)&W[(size_t)(k0 + kr) * DIM + n0 + c4];
    tl[(c4 + 0) * 72 + kr] = f2h(v.x);
    tl[(c4 + 1) * 72 + kr] = f2h(v.y);
    tl[(c4 + 2) * 72 + kr] = f2h(v.z);
    tl[(c4 + 3) * 72 + kr] = f2h(v.w);
  }
  __syncthreads();
#pragma unroll
  for (int i = 0; i < 2; i++) {
    int f = t + 256 * i;
    int nr = f >> 3, k8 = (f & 7) * 8;
    *(uint4*)&out[(size_t)(n0 + nr) * DIM + k0 + k8] = *(const uint4*)&tl[nr * 72 + k8];
  }
}

// ---------------------------------------------------------------------------
// proj (unchanged): qkv[z] = fp16(xh @ Wt[z]^T + b[z]).
// ---------------------------------------------------------------------------
__global__ __launch_bounds__(256) void proj_kernel(
    const unsigned short* __restrict__ xh, const unsigned short* __restrict__ Wt,
    const float* __restrict__ bq, const float* __restrict__ bk,
    const float* __restrict__ bv, unsigned short* __restrict__ outbase)
{
  const int z = blockIdx.z;
  const unsigned short* Wz = Wt + (size_t)z * DIM * DIM;
  const float* bias = (z == 0) ? bq : (z == 1) ? bk : bv;
  unsigned short* out = outbase + (size_t)z * BSZ * DIM;
  const int m0 = blockIdx.x * 128, n0 = blockIdx.y * 128;
  const int t = threadIdx.x, lane = t & 63, wave = t >> 6;
  const int wrow = (wave >> 1) * 64, wcol = (wave & 1) * 64;
  const int lr = lane & 15, lq = (lane >> 4) * 8;

  __shared__ unsigned short sm[128 * 132];
  unsigned short* As = sm;
  unsigned short* Bs = sm + 128 * 64;

  f32x4 acc[4][4];
  const f32x4 zero = {0.f, 0.f, 0.f, 0.f};
#pragma unroll
  for (int r = 0; r < 4; r++)
#pragma unroll
    for (int c = 0; c < 4; c++) acc[r][c] = zero;

  for (int k0 = 0; k0 < DIM; k0 += 64) {
    __syncthreads();
#pragma unroll
    for (int i = 0; i < 4; i++) {
      int f = t + 256 * i;
      int row = f >> 3, c8 = (f & 7) * 8;
      gl_lds16(&xh[(size_t)(m0 + row) * DIM + k0 + c8], &As[i * 2048 + wave * 512]);
      gl_lds16(&Wz[(size_t)(n0 + row) * DIM + k0 + c8], &Bs[i * 2048 + wave * 512]);
    }
    __syncthreads();
#pragma unroll
    for (int kk = 0; kk < 64; kk += 32) {
      half8 a[4], b[4];
#pragma unroll
      for (int r = 0; r < 4; r++) a[r] = ld_frag(&As[(wrow + 16 * r + lr) * 64 + kk + lq]);
#pragma unroll
      for (int c = 0; c < 4; c++) b[c] = ld_frag(&Bs[(wcol + 16 * c + lr) * 64 + kk + lq]);
#pragma unroll
      for (int r = 0; r < 4; r++)
#pragma unroll
        for (int c = 0; c < 4; c++)
          acc[r][c] = __builtin_amdgcn_mfma_f32_16x16x32_f16(a[r], b[c], acc[r][c], 0, 0, 0);
    }
  }
  __syncthreads();
#pragma unroll
  for (int c = 0; c < 4; c++) {
    float bb = bias[n0 + wcol + 16 * c + lr];
#pragma unroll
    for (int r = 0; r < 4; r++)
#pragma unroll
      for (int e = 0; e < 4; e++)
        sm[(wrow + 16 * r + (lane >> 4) * 4 + e) * 132 + wcol + 16 * c + lr] =
            f2h(acc[r][c][e] + bb);
  }
  __syncthreads();
#pragma unroll
  for (int i = 0; i < 8; i++) {
    int f = t + 256 * i;
    int row = f >> 4, c8 = (f & 15) * 8;
    *(uint4*)&out[(size_t)(m0 + row) * DIM + n0 + c8] = *(const uint4*)&sm[row * 132 + c8];
  }
}

// ---------------------------------------------------------------------------
__global__ __launch_bounds__(256) void vtrans_kernel(
    const unsigned short* __restrict__ vh, unsigned short* __restrict__ vt)
{
  const int b = blockIdx.z;
  const int s0 = blockIdx.x * 64, n0 = blockIdx.y * 64;
  const int t = threadIdx.x;
  __shared__ unsigned short tl[64 * 72];
#pragma unroll
  for (int i = 0; i < 2; i++) {
    int f = t + 256 * i;
    int sr = f >> 3, c8 = (f & 7) * 8;
    uint4 raw = *(const uint4*)&vh[((size_t)b * SEQ + s0 + sr) * DIM + n0 + c8];
    unsigned short u[8];
    *(uint4*)u = raw;
#pragma unroll
    for (int j = 0; j < 8; j++) tl[(c8 + j) * 72 + sr] = u[j];
  }
  __syncthreads();
#pragma unroll
  for (int i = 0; i < 2; i++) {
    int f = t + 256 * i;
    int nr = f >> 3, s8 = (f & 7) * 8;
    *(uint4*)&vt[((size_t)b * DIM + n0 + nr) * SEQ + s0 + s8] = *(const uint4*)&tl[nr * 72 + s8];
  }
}

// ---------------------------------------------------------------------------
// flash R9. Block = 64 Q rows, 4 waves: (kh = wave&1, rh = wave>>1).
// Per kt:
//   top bar_vm0 (K(kt) landed) -> issue vfA
//   -> A: 2x16 chained mfma_32x32x16, K+Q frags from LDS (S^T = K·Q^T)
//   -> max tree + shfl32 + mpart; bar#1 (lgkm: A-reads drained)
//   -> issue K(kt+1) (same Kbuf, reads done) + vfB
//   -> defer-max softmax: per-row keep m_run if growth<=8; P b64 writes;
//      lpart; ballot->fbuf; bar#2 -> lrun, uniform-skip rescale, pf (b64)
//   -> C: 64x mfma_16x16x32, dc0-3 vfA / dc4-7 vfB
// ---------------------------------------------------------------------------
#define PSTR 68   // Pbuf row stride (halves) = 34 dwords: bank base 2*row
#define OSTR 516  // Obuf row stride (floats)

__global__ __launch_bounds__(256, 1) void flash_kernel(
    const unsigned short* __restrict__ Qb, const unsigned short* __restrict__ Kb,
    const unsigned short* __restrict__ Vtb, float* __restrict__ Ob)
{
  const int zb = blockIdx.x & 7;          // batch -> XCD affinity
  const int q0 = (blockIdx.x >> 3) * 64;  // q-tile base row
  const unsigned short* Q = Qb + (size_t)zb * SEQ * DIM;
  const unsigned short* K = Kb + (size_t)zb * SEQ * DIM;
  const unsigned short* V = Vtb + (size_t)zb * DIM * SEQ;  // [d][s]
  float* Out = Ob + (size_t)zb * SEQ * DIM;

  const int t = threadIdx.x, lane = t & 63, wave = t >> 6;
  const int l31 = lane & 31, hi = lane >> 5;
  const int kh = wave & 1, rh = wave >> 1;
  const int lr = lane & 15, lq4 = lane >> 4;
  const float L2E = 1.4426950408889634f;

  // LDS carve (halves): Qbuf 32768 | Kbuf 32768 | Pbuf 64*68=4352 |
  // mpart 256 | lpart 256 | abuf 128 | lrun 128 | fbuf 8  = 70664 halves.
  __shared__ unsigned short lds[70664];
  unsigned short* Qbuf = lds;            // [64 rows][512], swizzled
  unsigned short* Kbuf = lds + 32768;    // [64 keys][512], swizzled
  unsigned short* Pbuf = lds + 65536;    // [64 rows][PSTR]
  float* mpart = (float*)(lds + 65536 + 64 * PSTR);
  float* lpart = mpart + 128;
  float* abuf = lpart + 128;
  float* lrun = abuf + 64;
  unsigned int* fbuf = (unsigned int*)(lrun + 64);  // per-wave keep flags

  if (t < 64) lrun[t] = 0.f;

  // staging offsets: tile [64 rows][512 halves], 64 chunks of 8h per row,
  // source chunk = lds chunk ^ (row&7).
  int koff[16];
#pragma unroll
  for (int i = 0; i < 16; i++) {
    int f = t + 256 * i;
    int row = f >> 6, c = f & 63;
    koff[i] = row * DIM + (c ^ (row & 7)) * 8;
  }

  // ---- stage Q -> Qbuf (resident), K(0) -> Kbuf; drained at loop-top bar ----
#pragma unroll
  for (int i = 0; i < 16; i++)
    gl_lds16(&Q[(size_t)q0 * DIM + koff[i]], &Qbuf[i * 2048 + wave * 512]);
#pragma unroll
  for (int i = 0; i < 16; i++)
    gl_lds16(&K[koff[i]], &Kbuf[i * 2048 + wave * 512]);

  // ---- running state ----
  f32x4 acc[32];  // [rg 0..3][dc 0..7]: row rg*16+lq4*4+e, d wave*128+dc*16+lr
  const f32x4 zero = {0.f, 0.f, 0.f, 0.f};
#pragma unroll
  for (int ob = 0; ob < 32; ob++) acc[ob] = zero;
  float m_run = -__builtin_inff();  // per lane: row rh*32 + l31

  const int keyrow = kh * 32 + l31, ksw = keyrow & 7;
  const int qrow = rh * 32 + l31, qsw = qrow & 7;
  const unsigned short* Kc = Kbuf + keyrow * 512;
  const unsigned short* Qc = Qbuf + qrow * 512;

  for (int kt = 0; kt < NT; kt++) {
    bar_vm0();  // K(kt) (and Q at kt=0) landed for all waves

    // ---- prefetch vfA: wave's d 0..63 slice (covered by phase A+B) ----
    const unsigned short* Vb = V + (size_t)(wave * 128 + lr) * SEQ + kt * KT + lq4 * 8;
    half8 vfA[8];
#pragma unroll
    for (int dc = 0; dc < 4; dc++)
#pragma unroll
      for (int ks = 0; ks < 2; ks++)
        vfA[dc * 2 + ks] = ld_frag(Vb + (size_t)dc * 16 * SEQ + ks * 32);

    // ===== phase A: S^T = K·Q^T, 2 independent chains (k 0..255 / 256..511) =====
    f32x16 s0 = {0.f, 0.f, 0.f, 0.f, 0.f, 0.f, 0.f, 0.f,
                 0.f, 0.f, 0.f, 0.f, 0.f, 0.f, 0.f, 0.f};
    f32x16 s1 = s0;
    __builtin_amdgcn_s_setprio(1);
#pragma unroll
    for (int j = 0; j < 16; j++) {
      half8 kf0 = ld_frag(&Kc[((2 * j + hi) ^ ksw) << 3]);
      half8 qv0 = ld_frag(&Qc[((2 * j + hi) ^ qsw) << 3]);
      half8 kf1 = ld_frag(&Kc[((2 * (j + 16) + hi) ^ ksw) << 3]);
      half8 qv1 = ld_frag(&Qc[((2 * (j + 16) + hi) ^ qsw) << 3]);
      s0 = __builtin_amdgcn_mfma_f32_32x32x16_f16(kf0, qv0, s0, 0, 0, 0);
      s1 = __builtin_amdgcn_mfma_f32_32x32x16_f16(kf1, qv1, s1, 0, 0, 0);
    }
    __builtin_amdgcn_s_setprio(0);
    f32x16 sacc = s0 + s1;

    // ===== phase B: defer-max online softmax (lane row rh*32+l31) =====
    float mx = sacc[0];
#pragma unroll
    for (int i2 = 1; i2 < 16; i2++) mx = fmaxf(mx, sacc[i2]);
    mx = fmaxf(mx, __shfl_xor(mx, 32, 64));
    if (lane < 32) mpart[kh * 64 + rh * 32 + lane] = mx;
    bar_lgkm();  // #1: mpart visible; ALL phase-A ds_reads drained block-wide

    // issue K(kt+1) into same Kbuf (A-reads done); earliest possible in-flight
    if (kt + 1 < NT) {
      const unsigned short* Kt = K + (size_t)(kt + 1) * KT * DIM;
#pragma unroll
      for (int i = 0; i < 16; i++)
        gl_lds16(&Kt[koff[i]], &Kbuf[i * 2048 + wave * 512]);
    }
    // vfB (d 64..127 of slice), covered by rest of B + C
    half8 vfB[8];
#pragma unroll
    for (int dc = 0; dc < 4; dc++)
#pragma unroll
      for (int ks = 0; ks < 2; ks++)
        vfB[dc * 2 + ks] = ld_frag(Vb + (size_t)(dc + 4) * 16 * SEQ + ks * 32);

    float mo = mpart[(kh ^ 1) * 64 + rh * 32 + l31];
    float mxc = fmaxf(mx, mo);
    // defer-max: keep m_run when growth <= 8 (P bounded by e^8 < f16 max)
    bool keep = (mxc - m_run <= 8.0f);
    float mnew = keep ? m_run : mxc;
    float alpha = keep ? 1.0f : exp2f((m_run - mnew) * L2E);
    m_run = mnew;
    if (kh == 0 && lane < 32) abuf[rh * 32 + lane] = alpha;
    unsigned long long ball = __ballot(keep);
    if (lane == 0) fbuf[wave] = (ball == ~0ull) ? 1u : 0u;

    // p = exp(S - m); pack 4 keys per b64 write (conflict-free with PSTR=68).
    // sacc reg r -> key (r&3) + 8*(r>>2) + 4*hi; group w2: regs 4w2..4w2+3
    // -> keys kh*32 + w2*8 + 4hi + {0..3}  (contiguous).
    float psum = 0.f;
#pragma unroll
    for (int w2 = 0; w2 < 4; w2++) {
      float p0 = exp2f((sacc[4 * w2 + 0] - mnew) * L2E);
      float p1 = exp2f((sacc[4 * w2 + 1] - mnew) * L2E);
      float p2 = exp2f((sacc[4 * w2 + 2] - mnew) * L2E);
      float p3 = exp2f((sacc[4 * w2 + 3] - mnew) * L2E);
      psum += (p0 + p1) + (p2 + p3);
      fp16x2 pa = __builtin_amdgcn_cvt_pkrtz(p0, p1);
      fp16x2 pb = __builtin_amdgcn_cvt_pkrtz(p2, p3);
      unsigned long long both =
          ((unsigned long long)__builtin_bit_cast(unsigned int, pb) << 32) |
          __builtin_bit_cast(unsigned int, pa);
      *(unsigned long long*)&Pbuf[qrow * PSTR + kh * 32 + w2 * 8 + 4 * hi] = both;
    }
    psum += __shfl_xor(psum, 32, 64);
    if (lane < 32) lpart[kh * 64 + rh * 32 + lane] = psum;
    bar_lgkm();  // #2: Pbuf, abuf, lpart, fbuf visible
    if (kh == 0 && lane < 32) {
      int r = rh * 32 + lane;
      lrun[r] = alpha * lrun[r] + lpart[r] + lpart[64 + r];
    }

    // ---- rescale acc only when some row moved its max (block-uniform) ----
    if (!(fbuf[0] & fbuf[1] & fbuf[2] & fbuf[3])) {
#pragma unroll
      for (int rg = 0; rg < 4; rg++)
#pragma unroll
        for (int e = 0; e < 4; e++) {
          float a = abuf[rg * 16 + lq4 * 4 + e];
#pragma unroll
          for (int dc = 0; dc < 8; dc++) acc[rg * 8 + dc][e] *= a;
        }
    }

    // ===== phase C: O += P V (wave: all 64 rows x its 128-d slice) =====
    // pf via 2x ds_read_b64 per frag (PSTR=68: b128 misaligned -> no fusion)
    half8 pf[4][2];
#pragma unroll
    for (int rg = 0; rg < 4; rg++)
#pragma unroll
      for (int ks = 0; ks < 2; ks++) {
        const unsigned short* pp = &Pbuf[(rg * 16 + lr) * PSTR + ks * 32 + lq4 * 8];
        half4 lo = *(const half4*)(const void*)pp;
        half4 h2 = *(const half4*)(const void*)(pp + 4);
        half8 v;
#pragma unroll
        for (int q = 0; q < 4; q++) { v[q] = lo[q]; v[4 + q] = h2[q]; }
        pf[rg][ks] = v;
      }
    __builtin_amdgcn_s_setprio(1);
#pragma unroll
    for (int dc = 0; dc < 4; dc++)
#pragma unroll
      for (int rg = 0; rg < 4; rg++) {
        acc[rg * 8 + dc] =
            __builtin_amdgcn_mfma_f32_16x16x32_f16(pf[rg][0], vfA[dc * 2 + 0],
                                                   acc[rg * 8 + dc], 0, 0, 0);
        acc[rg * 8 + dc] =
            __builtin_amdgcn_mfma_f32_16x16x32_f16(pf[rg][1], vfA[dc * 2 + 1],
                                                   acc[rg * 8 + dc], 0, 0, 0);
      }
#pragma unroll
    for (int dc = 4; dc < 8; dc++)
#pragma unroll
      for (int rg = 0; rg < 4; rg++) {
        acc[rg * 8 + dc] =
            __builtin_amdgcn_mfma_f32_16x16x32_f16(pf[rg][0], vfB[(dc - 4) * 2 + 0],
                                                   acc[rg * 8 + dc], 0, 0, 0);
        acc[rg * 8 + dc] =
            __builtin_amdgcn_mfma_f32_16x16x32_f16(pf[rg][1], vfB[(dc - 4) * 2 + 1],
                                                   acc[rg * 8 + dc], 0, 0, 0);
      }
    __builtin_amdgcn_s_setprio(0);
  }

  bar_lgkm_vm0();  // lrun final, all LDS quiesced before Obuf reuse

  // ---- finalize: O /= l, repack via LDS in 32-row halves, coalesced stores ----
  float linv[4][4];
#pragma unroll
  for (int rg = 0; rg < 4; rg++)
#pragma unroll
    for (int e = 0; e < 4; e++) linv[rg][e] = 1.0f / lrun[rg * 16 + lq4 * 4 + e];

  float* Obuf = (float*)lds;  // 32 x OSTR floats = 66 KB (over Qbuf/Kbuf)
#pragma unroll
  for (int h = 0; h < 2; h++) {
    __syncthreads();
#pragma unroll
    for (int r2 = 0; r2 < 2; r2++) {
      int rg = h * 2 + r2;
#pragma unroll
      for (int e = 0; e < 4; e++) {
        int rowh = r2 * 16 + lq4 * 4 + e;
#pragma unroll
        for (int dc = 0; dc < 8; dc++)
          Obuf[rowh * OSTR + wave * 128 + dc * 16 + lr] = acc[rg * 8 + dc][e] * linv[rg][e];
      }
    }
    __syncthreads();
#pragma unroll
    for (int i = 0; i < 16; i++) {
      int f = t + 256 * i;
      int rowh = f >> 7, c4 = (f & 127) * 4;
      *(float4*)&Out[(size_t)(q0 + h * 32 + rowh) * DIM + c4] =
          *(const float4*)&Obuf[rowh * OSTR + c4];
    }
  }
}

// ---------------------------------------------------------------------------
extern "C" void kernel_launch(void* const* d_in, const int* in_sizes, int n_in,
                              void* d_out, int out_size, void* d_ws, size_t ws_size,
                              hipStream_t stream)
{
  const float* X  = (const float*)d_in[0];
  const float* Wq = (const float*)d_in[1];
  const float* bq = (const float*)d_in[2];
  const float* Wk = (const float*)d_in[3];
  const float* bk = (const float*)d_in[4];
  const float* Wv = (const float*)d_in[5];
  const float* bv = (const float*)d_in[6];
  float* Out = (float*)d_out;

  char* ws = (char*)d_ws;
  const size_t MB = 1u << 20;
  unsigned short* qh = (unsigned short*)(ws);            // 16 MiB
  unsigned short* kh = (unsigned short*)(ws + 16 * MB);  // 16 MiB (proj z=1)
  unsigned short* vh = (unsigned short*)(ws + 32 * MB);  // 16 MiB (proj z=2)
  unsigned short* vt = (unsigned short*)(ws + 48 * MB);  // 16 MiB
  unsigned short* xh = (unsigned short*)(ws + 48 * MB);  // alias vt: dead pre-vtrans
  unsigned short* Wt = (unsigned short*)(ws + 64 * MB);  // 1.5 MiB

  cvt_x_kernel<<<dim3(BSZ * DIM / 2048), 256, 0, stream>>>(X, xh);
  cvt_w_kernel<<<dim3(8, 8, 3), 256, 0, stream>>>(Wq, Wk, Wv, Wt);
  proj_kernel<<<dim3(BSZ / 128, DIM / 128, 3), 256, 0, stream>>>(
      xh, Wt, bq, bk, bv, qh);
  vtrans_kernel<<<dim3(SEQ / 64, DIM / 64, NB), 256, 0, stream>>>(vh, vt);
  flash_kernel<<<dim3(NB * SEQ / 64), 256, 0, stream>>>(qh, kh, vt, Out);
}